// Round 6
// baseline (2286.646 us; speedup 1.0000x reference)
//
#include <hip/hip_runtime.h>

#define N_NODES 50000
#define N_EDGES 800000
#define N_GRAPHS 128
#define IN_CH 31
#define HID 64

// ---------------- CSR build ----------------

__global__ void hist_kernel(const int* __restrict__ dst, int* __restrict__ counts, int e) {
    int i = blockIdx.x * 256 + threadIdx.x;
    int i4 = i * 4;
    if (i4 + 4 <= e) {
        int4 d4 = *(const int4*)(dst + i4);
        atomicAdd(&counts[d4.x], 1);
        atomicAdd(&counts[d4.y], 1);
        atomicAdd(&counts[d4.z], 1);
        atomicAdd(&counts[d4.w], 1);
    } else {
        for (int j = i4; j < e; ++j) atomicAdd(&counts[dst[j]], 1);
    }
}

__global__ void scan_blocks_kernel(const int* __restrict__ counts, int* __restrict__ row_ptr,
                                   int* __restrict__ blk, int n) {
    __shared__ int tmp[256];
    int tid = threadIdx.x;
    int i = blockIdx.x * 256 + tid;
    int v = (i < n) ? counts[i] : 0;
    tmp[tid] = v;
    __syncthreads();
    for (int off = 1; off < 256; off <<= 1) {
        int u = (tid >= off) ? tmp[tid - off] : 0;
        __syncthreads();
        tmp[tid] += u;
        __syncthreads();
    }
    if (i < n) row_ptr[i + 1] = tmp[tid];
    if (tid == 255) blk[blockIdx.x] = tmp[255];
}

__global__ void scan_partials_kernel(int* __restrict__ blk, int nb) {
    __shared__ int tmp[256];
    int tid = threadIdx.x;
    int v = (tid < nb) ? blk[tid] : 0;
    tmp[tid] = v;
    __syncthreads();
    for (int off = 1; off < 256; off <<= 1) {
        int u = (tid >= off) ? tmp[tid - off] : 0;
        __syncthreads();
        tmp[tid] += u;
        __syncthreads();
    }
    if (tid < nb) blk[tid] = tmp[tid] - v;  // exclusive prefix
}

// also fills cursor[] = start offsets so scatter needs no second memset
__global__ void scan_add_kernel(int* __restrict__ row_ptr, const int* __restrict__ blk,
                                int* __restrict__ cursor, int n) {
    int i = blockIdx.x * 256 + threadIdx.x;
    if (i < n) {
        int v = row_ptr[i + 1] + blk[blockIdx.x];
        row_ptr[i + 1] = v;
        cursor[i + 1] = v;
    }
    if (i == 0) { row_ptr[0] = 0; cursor[0] = 0; }
}

__global__ void scatter_kernel(const int* __restrict__ src, const int* __restrict__ dst,
                               int* __restrict__ cursor, int* __restrict__ csr_src, int e) {
    int i = blockIdx.x * 256 + threadIdx.x;
    int i4 = i * 4;
    if (i4 + 4 <= e) {
        int4 s4 = *(const int4*)(src + i4);
        int4 d4 = *(const int4*)(dst + i4);
        csr_src[atomicAdd(&cursor[d4.x], 1)] = s4.x;
        csr_src[atomicAdd(&cursor[d4.y], 1)] = s4.y;
        csr_src[atomicAdd(&cursor[d4.z], 1)] = s4.z;
        csr_src[atomicAdd(&cursor[d4.w], 1)] = s4.w;
    } else {
        for (int j = i4; j < e; ++j) csr_src[atomicAdd(&cursor[dst[j]], 1)] = src[j];
    }
}

// ---------------- aggregation kernel (no LDS, no barriers) ----------------
// Wave per node, 4 waves per 256-thr block -> 8 waves/SIMD residency.
// Softmax-aggregation without max pass (shift-invariant; |t*x| <= ~8 fp32-safe).
// Scalarized loop control (readfirstlane) so 16 gathers issue back-to-back.
// Writes combined row aRows[d][0..63]:
//   C_IN==31: [aggr(31) | x(31) | 0 0],  C_IN==64: [aggr(64)] (x read separately).

template <int C_IN>
__global__ void __launch_bounds__(256, 8) aggr_kernel(
        const float* __restrict__ xin, const float* __restrict__ tptr,
        const int* __restrict__ row_ptr, const int* __restrict__ csr_src,
        float* __restrict__ aRows, int n) {
    int w = threadIdx.x >> 6, l = threadIdx.x & 63;
    int d = blockIdx.x * 4 + w;
    if (d >= n) return;
    float tval = tptr[0];
    int loff = (l < C_IN) ? l : 0;
    float xr = xin[d * C_IN + loff];
    int beg = __builtin_amdgcn_readfirstlane(row_ptr[d]);
    int end = __builtin_amdgcn_readfirstlane(row_ptr[d + 1]);
    float den = 0.f, num = 0.f;
    int base = beg;
    for (; base + 64 <= end; base += 64) {
        int sidx = csr_src[base + l];
        #pragma unroll
        for (int j = 0; j < 64; j += 16) {
            float v[16];
            #pragma unroll
            for (int i = 0; i < 16; ++i) {
                int s = __builtin_amdgcn_readlane(sidx, j + i);
                v[i] = xin[s * C_IN + loff];
            }
            #pragma unroll
            for (int i = 0; i < 16; ++i) {
                float e = __expf(tval * v[i]);
                den += e;
                num = fmaf(v[i], e, num);
            }
        }
    }
    int rem = end - base;                      // scalar, 0..63
    if (rem > 0) {
        int sidx = csr_src[base + ((l < rem) ? l : 0)];
        for (int j = 0; j < rem; j += 16) {    // scalar loop, usually 1 iter
            float v[16];
            #pragma unroll
            for (int i = 0; i < 16; ++i) {
                int jj = j + i;
                if (jj >= rem) jj = rem - 1;   // scalar clamp (safe dup)
                int s = __builtin_amdgcn_readlane(sidx, jj);
                v[i] = xin[s * C_IN + loff];
            }
            #pragma unroll
            for (int i = 0; i < 16; ++i) {
                float m = (j + i < rem) ? 1.f : 0.f;   // wave-uniform mask
                float e = __expf(tval * v[i]) * m;
                den += e;
                num = fmaf(v[i], e, num);
            }
        }
    }
    float aggr = (end > beg) ? num / den : 0.f;
    if (C_IN == 64) {
        aRows[d * 64 + l] = aggr;
    } else {
        float xs = __shfl(xr, (l - C_IN) & 63);   // lane l gets x-chan (l-31)
        float av = (l < C_IN) ? aggr : ((l < 2 * C_IN) ? xs : 0.f);
        aRows[d * 64 + l] = av;
    }
}

// ---------------- transform kernel (tiled matmul + norm + readout) ----------------
// Block = 1024 thr = 16 waves, 64 nodes/block. LDS: combined weights (K_TOT x 64)
// + 64 A-rows. Wave w computes full-K for nodes w*4..w*4+3: weight float4 read
// once per 4 nodes; A-row reads are wave-uniform LDS broadcasts (free).
// Then instance-norm (wave shuffle), ReLU, store, per-graph atomicMax.

template <int C_IN>
__global__ void __launch_bounds__(1024, 8) transform_kernel(
        const float* __restrict__ aRows, const float* __restrict__ xprev,
        const int* __restrict__ batch,
        const float* __restrict__ Wr, const float* __restrict__ br,
        const float* __restrict__ Ws,
        float* __restrict__ yout, float* __restrict__ hmax, int n) {
    constexpr int K_TOT = (C_IN == 64) ? 128 : 64;
    constexpr int K4    = K_TOT / 4;

    __shared__ float wLDS[K4 * 256];      // [k4][lane][4] : W[k][l]
    __shared__ float aLDS[64 * K_TOT];    // A[node][k]

    int tid = threadIdx.x;
    int w = tid >> 6, l = tid & 63;
    int nb = blockIdx.x * 64;

    // stage combined transposed weights, destination-ordered (conflict-free)
    for (int idx = tid; idx < K4 * 256; idx += 1024) {
        int k4 = idx >> 8;
        int ll = (idx >> 2) & 63;
        int k  = k4 * 4 + (idx & 3);
        float val;
        if (C_IN == 64) {
            val = (k < 64) ? Wr[ll * 64 + k] : Ws[ll * 64 + (k - 64)];
        } else {
            val = (k < C_IN) ? Wr[ll * C_IN + k]
                : (k < 2 * C_IN) ? Ws[ll * C_IN + (k - C_IN)] : 0.f;
        }
        wLDS[idx] = val;
    }
    // stage A rows (coalesced global reads, destination-ordered LDS writes)
    for (int idx = tid; idx < 64 * K_TOT; idx += 1024) {
        int j = idx / K_TOT, k = idx % K_TOT;
        int node = nb + j;
        if (node >= n) node = n - 1;
        float val;
        if (C_IN == 64) {
            val = (k < 64) ? aRows[node * 64 + k] : xprev[node * 64 + (k - 64)];
        } else {
            val = aRows[node * 64 + k];
        }
        aLDS[idx] = val;
    }
    __syncthreads();

    int n0 = w * 4;
    float acc0 = 0.f, acc1 = 0.f, acc2 = 0.f, acc3 = 0.f;
    #pragma unroll
    for (int k4 = 0; k4 < K4; ++k4) {
        float4 w4 = *(const float4*)&wLDS[k4 * 256 + l * 4];
        float4 a0 = *(const float4*)&aLDS[(n0 + 0) * K_TOT + k4 * 4];
        float4 a1 = *(const float4*)&aLDS[(n0 + 1) * K_TOT + k4 * 4];
        float4 a2 = *(const float4*)&aLDS[(n0 + 2) * K_TOT + k4 * 4];
        float4 a3 = *(const float4*)&aLDS[(n0 + 3) * K_TOT + k4 * 4];
        acc0 = fmaf(a0.x, w4.x, acc0); acc0 = fmaf(a0.y, w4.y, acc0);
        acc0 = fmaf(a0.z, w4.z, acc0); acc0 = fmaf(a0.w, w4.w, acc0);
        acc1 = fmaf(a1.x, w4.x, acc1); acc1 = fmaf(a1.y, w4.y, acc1);
        acc1 = fmaf(a1.z, w4.z, acc1); acc1 = fmaf(a1.w, w4.w, acc1);
        acc2 = fmaf(a2.x, w4.x, acc2); acc2 = fmaf(a2.y, w4.y, acc2);
        acc2 = fmaf(a2.z, w4.z, acc2); acc2 = fmaf(a2.w, w4.w, acc2);
        acc3 = fmaf(a3.x, w4.x, acc3); acc3 = fmaf(a3.y, w4.y, acc3);
        acc3 = fmaf(a3.z, w4.z, acc3); acc3 = fmaf(a3.w, w4.w, acc3);
    }

    float bias = br[l];
    float accs[4] = {acc0, acc1, acc2, acc3};
    #pragma unroll
    for (int j = 0; j < 4; ++j) {
        int d = nb + n0 + j;
        if (d < n) {
            float acc = accs[j] + bias;
            float s = acc;
            for (int off = 32; off > 0; off >>= 1) s += __shfl_xor(s, off);
            float mu = s * (1.0f / 64.0f);
            float dc = acc - mu;
            float s2 = dc * dc;
            for (int off = 32; off > 0; off >>= 1) s2 += __shfl_xor(s2, off);
            float var = s2 * (1.0f / 64.0f);
            float y = dc * rsqrtf(var + 1e-5f);
            y = fmaxf(y, 0.f);
            yout[d * 64 + l] = y;
            int g = batch[d];
            // y >= 0 and hmax zero-initialized: int-punned atomicMax order-correct
            atomicMax((int*)&hmax[g * 64 + l], __float_as_int(y));
        }
    }
}

// ---------------- MLP head ----------------

__global__ void mlp_kernel(const float* __restrict__ h,  // [3][G][64]
                           const float* __restrict__ Wl1, const float* __restrict__ bl1,
                           const float* __restrict__ Wl2, const float* __restrict__ bl2,
                           float* __restrict__ out) {
    __shared__ float hrow[192];
    __shared__ float z1[128];
    __shared__ float z2[32];
    __shared__ float snorm;
    int g = blockIdx.x, tid = threadIdx.x;  // 128 threads
    if (tid < 64) {
        hrow[tid]       = h[0 * N_GRAPHS * 64 + g * 64 + tid];
        hrow[64 + tid]  = h[1 * N_GRAPHS * 64 + g * 64 + tid];
        hrow[128 + tid] = h[2 * N_GRAPHS * 64 + g * 64 + tid];
    }
    __syncthreads();
    float acc = bl1[tid];
    #pragma unroll 8
    for (int c = 0; c < 192; ++c) acc = fmaf(hrow[c], Wl1[tid * 192 + c], acc);
    z1[tid] = fmaxf(acc, 0.f);
    __syncthreads();
    if (tid < 32) {
        float a2 = bl2[tid];
        #pragma unroll 8
        for (int c = 0; c < 128; ++c) a2 = fmaf(z1[c], Wl2[tid * 128 + c], a2);
        z2[tid] = a2;
    }
    __syncthreads();
    if (tid == 0) {
        float ss = 0.f;
        for (int i = 0; i < 32; ++i) ss += z2[i] * z2[i];
        snorm = fmaxf(sqrtf(ss), 1e-12f);
    }
    __syncthreads();
    if (tid < 32) out[g * 32 + tid] = z2[tid] / snorm;
}

// ---------------- launch ----------------

extern "C" void kernel_launch(void* const* d_in, const int* in_sizes, int n_in,
                              void* d_out, int out_size, void* d_ws, size_t ws_size,
                              hipStream_t stream) {
    const float* x   = (const float*)d_in[0];
    const int* eidx  = (const int*)d_in[1];
    const int* batch = (const int*)d_in[2];
    const float* t   = (const float*)d_in[3];
    const float* W1r = (const float*)d_in[4];
    const float* b1  = (const float*)d_in[5];
    const float* W1s = (const float*)d_in[6];
    const float* W2r = (const float*)d_in[7];
    const float* b2  = (const float*)d_in[8];
    const float* W2s = (const float*)d_in[9];
    const float* W3r = (const float*)d_in[10];
    const float* b3  = (const float*)d_in[11];
    const float* W3s = (const float*)d_in[12];
    const float* Wl1 = (const float*)d_in[13];
    const float* bl1 = (const float*)d_in[14];
    const float* Wl2 = (const float*)d_in[15];
    const float* bl2 = (const float*)d_in[16];
    float* out = (float*)d_out;

    const int nE = in_sizes[1] / 2;
    const int nN = in_sizes[2];
    const int* src = eidx;
    const int* dst = eidx + nE;

    char* ws = (char*)d_ws;
    size_t off = 0;
    auto alloc = [&](size_t bytes) {
        char* p = ws + off;
        off = (off + bytes + 255) & ~(size_t)255;
        return p;
    };
    int*   counts  = (int*)alloc((size_t)nN * 4);
    int*   row_ptr = (int*)alloc((size_t)(nN + 1) * 4);
    int*   cursor  = (int*)alloc((size_t)(nN + 1) * 4);
    int*   blk     = (int*)alloc(256 * 4);
    int*   csr_src = (int*)alloc((size_t)nE * 4);
    float* aRows   = (float*)alloc((size_t)nN * 64 * 4);
    float* yA      = (float*)alloc((size_t)nN * 64 * 4);
    float* yB      = (float*)alloc((size_t)nN * 64 * 4);
    float* h       = (float*)alloc((size_t)3 * N_GRAPHS * 64 * 4);

    const int nbE4 = (nE / 4 + 255) / 256 + 1;
    const int nbN  = (nN + 255) / 256;

    hipMemsetAsync(counts, 0, (size_t)nN * 4, stream);
    hist_kernel<<<nbE4, 256, 0, stream>>>(dst, counts, nE);
    scan_blocks_kernel<<<nbN, 256, 0, stream>>>(counts, row_ptr, blk, nN);
    scan_partials_kernel<<<1, 256, 0, stream>>>(blk, nbN);
    scan_add_kernel<<<nbN, 256, 0, stream>>>(row_ptr, blk, cursor, nN);
    scatter_kernel<<<nbE4, 256, 0, stream>>>(src, dst, cursor, csr_src, nE);
    hipMemsetAsync(h, 0, (size_t)3 * N_GRAPHS * 64 * 4, stream);

    const int nbA = (nN + 3) / 4;
    const int nbT = (nN + 63) / 64;

    aggr_kernel<IN_CH><<<nbA, 256, 0, stream>>>(x, t, row_ptr, csr_src, aRows, nN);
    transform_kernel<IN_CH><<<nbT, 1024, 0, stream>>>(aRows, nullptr, batch,
                                                      W1r, b1, W1s, yA, h + 0 * N_GRAPHS * 64, nN);
    aggr_kernel<HID><<<nbA, 256, 0, stream>>>(yA, t, row_ptr, csr_src, aRows, nN);
    transform_kernel<HID><<<nbT, 1024, 0, stream>>>(aRows, yA, batch,
                                                    W2r, b2, W2s, yB, h + 1 * N_GRAPHS * 64, nN);
    aggr_kernel<HID><<<nbA, 256, 0, stream>>>(yB, t, row_ptr, csr_src, aRows, nN);
    transform_kernel<HID><<<nbT, 1024, 0, stream>>>(aRows, yB, batch,
                                                    W3r, b3, W3s, yA, h + 2 * N_GRAPHS * 64, nN);
    mlp_kernel<<<N_GRAPHS, 128, 0, stream>>>(h, Wl1, bl1, Wl2, bl2, out);
}

// Round 7
// 391.421 us; speedup vs baseline: 5.8419x; 5.8419x over previous
//
#include <hip/hip_runtime.h>

#define N_NODES 50000
#define N_EDGES 800000
#define N_GRAPHS 128
#define IN_CH 31
#define HID 64

// ---------------- CSR build ----------------

__global__ void hist_kernel(const int* __restrict__ dst, int* __restrict__ counts, int e) {
    int i = blockIdx.x * 256 + threadIdx.x;
    int i4 = i * 4;
    if (i4 + 4 <= e) {
        int4 d4 = *(const int4*)(dst + i4);
        atomicAdd(&counts[d4.x], 1);
        atomicAdd(&counts[d4.y], 1);
        atomicAdd(&counts[d4.z], 1);
        atomicAdd(&counts[d4.w], 1);
    } else {
        for (int j = i4; j < e; ++j) atomicAdd(&counts[dst[j]], 1);
    }
}

__global__ void scan_blocks_kernel(const int* __restrict__ counts, int* __restrict__ row_ptr,
                                   int* __restrict__ blk, int n) {
    __shared__ int tmp[256];
    int tid = threadIdx.x;
    int i = blockIdx.x * 256 + tid;
    int v = (i < n) ? counts[i] : 0;
    tmp[tid] = v;
    __syncthreads();
    for (int off = 1; off < 256; off <<= 1) {
        int u = (tid >= off) ? tmp[tid - off] : 0;
        __syncthreads();
        tmp[tid] += u;
        __syncthreads();
    }
    if (i < n) row_ptr[i + 1] = tmp[tid];
    if (tid == 255) blk[blockIdx.x] = tmp[255];
}

__global__ void scan_partials_kernel(int* __restrict__ blk, int nb) {
    __shared__ int tmp[256];
    int tid = threadIdx.x;
    int v = (tid < nb) ? blk[tid] : 0;
    tmp[tid] = v;
    __syncthreads();
    for (int off = 1; off < 256; off <<= 1) {
        int u = (tid >= off) ? tmp[tid - off] : 0;
        __syncthreads();
        tmp[tid] += u;
        __syncthreads();
    }
    if (tid < nb) blk[tid] = tmp[tid] - v;  // exclusive prefix
}

// also fills cursor[] = start offsets so scatter needs no second memset
__global__ void scan_add_kernel(int* __restrict__ row_ptr, const int* __restrict__ blk,
                                int* __restrict__ cursor, int n) {
    int i = blockIdx.x * 256 + threadIdx.x;
    if (i < n) {
        int v = row_ptr[i + 1] + blk[blockIdx.x];
        row_ptr[i + 1] = v;
        cursor[i + 1] = v;
    }
    if (i == 0) { row_ptr[0] = 0; cursor[0] = 0; }
}

__global__ void scatter_kernel(const int* __restrict__ src, const int* __restrict__ dst,
                               int* __restrict__ cursor, int* __restrict__ csr_src, int e) {
    int i = blockIdx.x * 256 + threadIdx.x;
    int i4 = i * 4;
    if (i4 + 4 <= e) {
        int4 s4 = *(const int4*)(src + i4);
        int4 d4 = *(const int4*)(dst + i4);
        csr_src[atomicAdd(&cursor[d4.x], 1)] = s4.x;
        csr_src[atomicAdd(&cursor[d4.y], 1)] = s4.y;
        csr_src[atomicAdd(&cursor[d4.z], 1)] = s4.z;
        csr_src[atomicAdd(&cursor[d4.w], 1)] = s4.w;
    } else {
        for (int j = i4; j < e; ++j) csr_src[atomicAdd(&cursor[dst[j]], 1)] = src[j];
    }
}

// ---------------- aggregation kernel (no LDS, no barriers) ----------------
// Wave per node, 4 waves per 256-thr block -> 8 waves/SIMD residency.
// Softmax-aggregation without max pass (shift-invariant; |t*x| <= ~8 fp32-safe).
// Scalarized loop control (readfirstlane) so 16 gathers issue back-to-back.
// Writes combined row aRows[d][0..63]:
//   C_IN==31: [aggr(31) | x(31) | 0 0],  C_IN==64: [aggr(64)] (x read separately).

template <int C_IN>
__global__ void __launch_bounds__(256, 8) aggr_kernel(
        const float* __restrict__ xin, const float* __restrict__ tptr,
        const int* __restrict__ row_ptr, const int* __restrict__ csr_src,
        float* __restrict__ aRows, int n) {
    int w = threadIdx.x >> 6, l = threadIdx.x & 63;
    int d = blockIdx.x * 4 + w;
    if (d >= n) return;
    float tval = tptr[0];
    int loff = (l < C_IN) ? l : 0;
    float xr = xin[d * C_IN + loff];
    int beg = __builtin_amdgcn_readfirstlane(row_ptr[d]);
    int end = __builtin_amdgcn_readfirstlane(row_ptr[d + 1]);
    float den = 0.f, num = 0.f;
    int base = beg;
    for (; base + 64 <= end; base += 64) {
        int sidx = csr_src[base + l];
        #pragma unroll
        for (int j = 0; j < 64; j += 16) {
            float v[16];
            #pragma unroll
            for (int i = 0; i < 16; ++i) {
                int s = __builtin_amdgcn_readlane(sidx, j + i);
                v[i] = xin[s * C_IN + loff];
            }
            #pragma unroll
            for (int i = 0; i < 16; ++i) {
                float e = __expf(tval * v[i]);
                den += e;
                num = fmaf(v[i], e, num);
            }
        }
    }
    int rem = end - base;                      // scalar, 0..63
    if (rem > 0) {
        int sidx = csr_src[base + ((l < rem) ? l : 0)];
        for (int j = 0; j < rem; j += 16) {    // scalar loop, usually 1 iter
            float v[16];
            #pragma unroll
            for (int i = 0; i < 16; ++i) {
                int jj = j + i;
                if (jj >= rem) jj = rem - 1;   // scalar clamp (safe dup)
                int s = __builtin_amdgcn_readlane(sidx, jj);
                v[i] = xin[s * C_IN + loff];
            }
            #pragma unroll
            for (int i = 0; i < 16; ++i) {
                float m = (j + i < rem) ? 1.f : 0.f;   // wave-uniform mask
                float e = __expf(tval * v[i]) * m;
                den += e;
                num = fmaf(v[i], e, num);
            }
        }
    }
    float aggr = (end > beg) ? num / den : 0.f;
    if (C_IN == 64) {
        aRows[d * 64 + l] = aggr;
    } else {
        float xs = __shfl(xr, (l - C_IN) & 63);   // lane l gets x-chan (l-31)
        float av = (l < C_IN) ? aggr : ((l < 2 * C_IN) ? xs : 0.f);
        aRows[d * 64 + l] = av;
    }
}

// ---------------- transform kernel (tiled matmul + norm + readout) ----------------
// Block = 1024 thr = 16 waves, 64 nodes/block. LDS: combined weights (K_TOT x 64)
// + 64 A-rows. Wave w computes full-K for nodes w*4..w*4+3.
// K-loop unroll capped at 2: full unroll (32 iters x 5 float4 LDS loads) hoisted
// ~160 float4 temps past the 64-VGPR cap from __launch_bounds__(1024,8) and
// spilled ~1.5 GB to scratch (round 6: WRITE_SIZE 1.48 GB, 832 us, VALUBusy 2%).

template <int C_IN>
__global__ void __launch_bounds__(1024, 8) transform_kernel(
        const float* __restrict__ aRows, const float* __restrict__ xprev,
        const int* __restrict__ batch,
        const float* __restrict__ Wr, const float* __restrict__ br,
        const float* __restrict__ Ws,
        float* __restrict__ yout, float* __restrict__ hmax, int n) {
    constexpr int K_TOT = (C_IN == 64) ? 128 : 64;
    constexpr int K4    = K_TOT / 4;

    __shared__ float wLDS[K4 * 256];      // [k4][lane][4] : W[k][l]
    __shared__ float aLDS[64 * K_TOT];    // A[node][k]

    int tid = threadIdx.x;
    int w = tid >> 6, l = tid & 63;
    int nb = blockIdx.x * 64;

    // stage combined transposed weights, destination-ordered (conflict-free)
    for (int idx = tid; idx < K4 * 256; idx += 1024) {
        int k4 = idx >> 8;
        int ll = (idx >> 2) & 63;
        int k  = k4 * 4 + (idx & 3);
        float val;
        if (C_IN == 64) {
            val = (k < 64) ? Wr[ll * 64 + k] : Ws[ll * 64 + (k - 64)];
        } else {
            val = (k < C_IN) ? Wr[ll * C_IN + k]
                : (k < 2 * C_IN) ? Ws[ll * C_IN + (k - C_IN)] : 0.f;
        }
        wLDS[idx] = val;
    }
    // stage A rows (coalesced global reads, destination-ordered LDS writes)
    for (int idx = tid; idx < 64 * K_TOT; idx += 1024) {
        int j = idx / K_TOT, k = idx % K_TOT;
        int node = nb + j;
        if (node >= n) node = n - 1;
        float val;
        if (C_IN == 64) {
            val = (k < 64) ? aRows[node * 64 + k] : xprev[node * 64 + (k - 64)];
        } else {
            val = aRows[node * 64 + k];
        }
        aLDS[idx] = val;
    }
    __syncthreads();

    int n0 = w * 4;
    float acc0 = 0.f, acc1 = 0.f, acc2 = 0.f, acc3 = 0.f;
    #pragma unroll 2
    for (int k4 = 0; k4 < K4; ++k4) {
        float4 w4 = *(const float4*)&wLDS[k4 * 256 + l * 4];
        float4 a0 = *(const float4*)&aLDS[(n0 + 0) * K_TOT + k4 * 4];
        float4 a1 = *(const float4*)&aLDS[(n0 + 1) * K_TOT + k4 * 4];
        float4 a2 = *(const float4*)&aLDS[(n0 + 2) * K_TOT + k4 * 4];
        float4 a3 = *(const float4*)&aLDS[(n0 + 3) * K_TOT + k4 * 4];
        acc0 = fmaf(a0.x, w4.x, acc0); acc0 = fmaf(a0.y, w4.y, acc0);
        acc0 = fmaf(a0.z, w4.z, acc0); acc0 = fmaf(a0.w, w4.w, acc0);
        acc1 = fmaf(a1.x, w4.x, acc1); acc1 = fmaf(a1.y, w4.y, acc1);
        acc1 = fmaf(a1.z, w4.z, acc1); acc1 = fmaf(a1.w, w4.w, acc1);
        acc2 = fmaf(a2.x, w4.x, acc2); acc2 = fmaf(a2.y, w4.y, acc2);
        acc2 = fmaf(a2.z, w4.z, acc2); acc2 = fmaf(a2.w, w4.w, acc2);
        acc3 = fmaf(a3.x, w4.x, acc3); acc3 = fmaf(a3.y, w4.y, acc3);
        acc3 = fmaf(a3.z, w4.z, acc3); acc3 = fmaf(a3.w, w4.w, acc3);
    }

    float bias = br[l];
    float accs[4] = {acc0, acc1, acc2, acc3};
    #pragma unroll
    for (int j = 0; j < 4; ++j) {
        int d = nb + n0 + j;
        if (d < n) {
            float acc = accs[j] + bias;
            float s = acc;
            for (int off = 32; off > 0; off >>= 1) s += __shfl_xor(s, off);
            float mu = s * (1.0f / 64.0f);
            float dc = acc - mu;
            float s2 = dc * dc;
            for (int off = 32; off > 0; off >>= 1) s2 += __shfl_xor(s2, off);
            float var = s2 * (1.0f / 64.0f);
            float y = dc * rsqrtf(var + 1e-5f);
            y = fmaxf(y, 0.f);
            yout[d * 64 + l] = y;
            int g = batch[d];
            // y >= 0 and hmax zero-initialized: int-punned atomicMax order-correct
            atomicMax((int*)&hmax[g * 64 + l], __float_as_int(y));
        }
    }
}

// ---------------- MLP head ----------------

__global__ void mlp_kernel(const float* __restrict__ h,  // [3][G][64]
                           const float* __restrict__ Wl1, const float* __restrict__ bl1,
                           const float* __restrict__ Wl2, const float* __restrict__ bl2,
                           float* __restrict__ out) {
    __shared__ float hrow[192];
    __shared__ float z1[128];
    __shared__ float z2[32];
    __shared__ float snorm;
    int g = blockIdx.x, tid = threadIdx.x;  // 128 threads
    if (tid < 64) {
        hrow[tid]       = h[0 * N_GRAPHS * 64 + g * 64 + tid];
        hrow[64 + tid]  = h[1 * N_GRAPHS * 64 + g * 64 + tid];
        hrow[128 + tid] = h[2 * N_GRAPHS * 64 + g * 64 + tid];
    }
    __syncthreads();
    float acc = bl1[tid];
    #pragma unroll 8
    for (int c = 0; c < 192; ++c) acc = fmaf(hrow[c], Wl1[tid * 192 + c], acc);
    z1[tid] = fmaxf(acc, 0.f);
    __syncthreads();
    if (tid < 32) {
        float a2 = bl2[tid];
        #pragma unroll 8
        for (int c = 0; c < 128; ++c) a2 = fmaf(z1[c], Wl2[tid * 128 + c], a2);
        z2[tid] = a2;
    }
    __syncthreads();
    if (tid == 0) {
        float ss = 0.f;
        for (int i = 0; i < 32; ++i) ss += z2[i] * z2[i];
        snorm = fmaxf(sqrtf(ss), 1e-12f);
    }
    __syncthreads();
    if (tid < 32) out[g * 32 + tid] = z2[tid] / snorm;
}

// ---------------- launch ----------------

extern "C" void kernel_launch(void* const* d_in, const int* in_sizes, int n_in,
                              void* d_out, int out_size, void* d_ws, size_t ws_size,
                              hipStream_t stream) {
    const float* x   = (const float*)d_in[0];
    const int* eidx  = (const int*)d_in[1];
    const int* batch = (const int*)d_in[2];
    const float* t   = (const float*)d_in[3];
    const float* W1r = (const float*)d_in[4];
    const float* b1  = (const float*)d_in[5];
    const float* W1s = (const float*)d_in[6];
    const float* W2r = (const float*)d_in[7];
    const float* b2  = (const float*)d_in[8];
    const float* W2s = (const float*)d_in[9];
    const float* W3r = (const float*)d_in[10];
    const float* b3  = (const float*)d_in[11];
    const float* W3s = (const float*)d_in[12];
    const float* Wl1 = (const float*)d_in[13];
    const float* bl1 = (const float*)d_in[14];
    const float* Wl2 = (const float*)d_in[15];
    const float* bl2 = (const float*)d_in[16];
    float* out = (float*)d_out;

    const int nE = in_sizes[1] / 2;
    const int nN = in_sizes[2];
    const int* src = eidx;
    const int* dst = eidx + nE;

    char* ws = (char*)d_ws;
    size_t off = 0;
    auto alloc = [&](size_t bytes) {
        char* p = ws + off;
        off = (off + bytes + 255) & ~(size_t)255;
        return p;
    };
    int*   counts  = (int*)alloc((size_t)nN * 4);
    int*   row_ptr = (int*)alloc((size_t)(nN + 1) * 4);
    int*   cursor  = (int*)alloc((size_t)(nN + 1) * 4);
    int*   blk     = (int*)alloc(256 * 4);
    int*   csr_src = (int*)alloc((size_t)nE * 4);
    float* aRows   = (float*)alloc((size_t)nN * 64 * 4);
    float* yA      = (float*)alloc((size_t)nN * 64 * 4);
    float* yB      = (float*)alloc((size_t)nN * 64 * 4);
    float* h       = (float*)alloc((size_t)3 * N_GRAPHS * 64 * 4);

    const int nbE4 = (nE / 4 + 255) / 256 + 1;
    const int nbN  = (nN + 255) / 256;

    hipMemsetAsync(counts, 0, (size_t)nN * 4, stream);
    hist_kernel<<<nbE4, 256, 0, stream>>>(dst, counts, nE);
    scan_blocks_kernel<<<nbN, 256, 0, stream>>>(counts, row_ptr, blk, nN);
    scan_partials_kernel<<<1, 256, 0, stream>>>(blk, nbN);
    scan_add_kernel<<<nbN, 256, 0, stream>>>(row_ptr, blk, cursor, nN);
    scatter_kernel<<<nbE4, 256, 0, stream>>>(src, dst, cursor, csr_src, nE);
    hipMemsetAsync(h, 0, (size_t)3 * N_GRAPHS * 64 * 4, stream);

    const int nbA = (nN + 3) / 4;
    const int nbT = (nN + 63) / 64;

    aggr_kernel<IN_CH><<<nbA, 256, 0, stream>>>(x, t, row_ptr, csr_src, aRows, nN);
    transform_kernel<IN_CH><<<nbT, 1024, 0, stream>>>(aRows, nullptr, batch,
                                                      W1r, b1, W1s, yA, h + 0 * N_GRAPHS * 64, nN);
    aggr_kernel<HID><<<nbA, 256, 0, stream>>>(yA, t, row_ptr, csr_src, aRows, nN);
    transform_kernel<HID><<<nbT, 1024, 0, stream>>>(aRows, yA, batch,
                                                    W2r, b2, W2s, yB, h + 1 * N_GRAPHS * 64, nN);
    aggr_kernel<HID><<<nbA, 256, 0, stream>>>(yB, t, row_ptr, csr_src, aRows, nN);
    transform_kernel<HID><<<nbT, 1024, 0, stream>>>(aRows, yB, batch,
                                                    W3r, b3, W3s, yA, h + 2 * N_GRAPHS * 64, nN);
    mlp_kernel<<<N_GRAPHS, 128, 0, stream>>>(h, Wl1, bl1, Wl2, bl2, out);
}